// Round 10
// baseline (61.144 us; speedup 1.0000x reference)
//
#include <hip/hip_runtime.h>

#define PRECS 1e-6f

// raw hardware transcendentals: v_exp_f32 / v_log_f32 (base-2).
// fpow(0, e>0) == 0 exactly: log2(0)=-inf -> exp2(-inf)=0.
__device__ __forceinline__ float fpow(float b, float e) {
    return __builtin_amdgcn_exp2f(e * __builtin_amdgcn_logf(b));
}

__device__ __forceinline__ float frcp(float v) {
    return __builtin_amdgcn_rcpf(v);
}

__device__ __forceinline__ float med3(float a, float b, float c) {
    return __builtin_amdgcn_fmed3f(a, b, c);
}

template <int CTRL>
__device__ __forceinline__ float dpp_mov(float v) {
    return __int_as_float(
        __builtin_amdgcn_update_dpp(0, __float_as_int(v), CTRL, 0xF, 0xF, true));
}

// sum over each 8-lane group, entirely on the VALU pipe (DPP, no LDS)
__device__ __forceinline__ float rsum8(float v) {
    v += dpp_mov<0xB1>(v);   // quad_perm [1,0,3,2]  : lane ^= 1
    v += dpp_mov<0x4E>(v);   // quad_perm [2,3,0,1]  : lane ^= 2
    v += dpp_mov<0x141>(v);  // row_half_mirror      : lane -> 7-lane within 8
    return v;
}

// workgroup-scope flag sync (LDS). Release store orders the wave's prior
// ds_writes (lgkmcnt drain); acquire load orders subsequent ds_reads.
__device__ __forceinline__ void waitge(int* f, int v) {
    while (__hip_atomic_load(f, __ATOMIC_ACQUIRE, __HIP_MEMORY_SCOPE_WORKGROUP) < v)
        __builtin_amdgcn_s_sleep(1);
}
__device__ __forceinline__ void setflag(int* f, int v) {
    if ((threadIdx.x & 63) == 0)
        __hip_atomic_store(f, v, __ATOMIC_RELEASE, __HIP_MEMORY_SCOPE_WORKGROUP);
}

// ASYNCHRONOUS 4-stage wave-specialized pipeline over 16-step blocks.
// No __syncthreads in steady state: stages chase each other through
// depth-2/4 LDS buffers gated by per-stage block counters. The pacing
// stage (B: the S-curve's irreducible 2-pow serial chain) free-runs;
// all other stages have >= 1 block of slack on every gate.
__global__ __launch_bounds__(256, 1) void xaj_kernel(
    const float* __restrict__ x,     // (365, 2000, 3)
    const float* __restrict__ prm,   // (2000, 12, 8)
    float* __restrict__ out)         // (365, 2000, 5)
{
    constexpr int Nstep = 365, Ngrid = 2000;
    constexpr int xstride = Ngrid * 3;
    constexpr int K = 16;            // steps per pipeline block
    constexpr int NBLK = 23;         // 23*16 = 368 padded steps

    const int wid  = (int)threadIdx.x >> 6;   // 0=A, 1=B, 2=C, 3=D
    const int lane = (int)threadIdx.x & 63;
    const int g = blockIdx.x * 8 + (lane >> 3);   // 250 blocks * 8 grids = 2000
    const int m = lane & 7;

    __shared__ float2 stIn[4][K][64];   // {P, PET*KE}             (C -> A)
    __shared__ float4 stA[4][K][64];    // {PE, R_per, E, PEc}     (A -> C,B,D)
    __shared__ float4 stFR[2][K][64];   // {FR, r2, giFR, RpiFR}   (C -> B)
    __shared__ float2 stB[2][K][64];    // {RS, FR*Sn}             (B -> D)
    __shared__ int flg[8];  // 0:cIn staged, 1:aDone, 2:frDone, 3:bDone, 4:dDone

    const float lo[12] = {0.3f,0.0f,0.01f,0.01f,0.01f,0.09f,0.01f,0.0f,0.01f,0.01f,0.0f,0.0f};
    const float hi[12] = {2.0f,5.0f,100.0f,100.0f,200.0f,1.0f,100.0f,10.0f,0.7f,0.7f,0.998f,0.998f};
    float p[12];
    const float* pb = prm + (size_t)g * 96 + m;
#pragma unroll
    for (int i = 0; i < 12; ++i)
        p[i] = lo[i] + pb[i * 8] * (hi[i] - lo[i]);

    const float KE=p[0], B=p[1], WUM=p[2], WLM=p[3], WM=p[4], C=p[5],
                SM=p[6], EX=p[7], KI_=p[8], KG_=p[9], CI=p[10], CG=p[11];

    // loop-invariant derived constants
    const float wdm  = fmaxf(WM - WUM - WLM, 0.f);
    const float sumk = KI_ + KG_;
    const float nrm  = (1.f - PRECS) / (sumk + PRECS);
    const float KI   = (sumk < 1.f) ? KI_ : KI_ * nrm;
    const float KG   = (sumk < 1.f) ? KG_ : KG_ * nrm;
    const float expB = 1.f + B,  invB  = 1.f / expB;
    const float WMM  = WM * expB;
    const float expEX= 1.f + EX, invEX = 1.f / expEX;
    const float SMM  = SM * expEX;
    const float inv_WLM = 1.f / (WLM + PRECS);
    const float inv_WM  = 1.f / (WM  + PRECS);
    const float inv_WMM = 1.f / (WMM + PRECS);
    const float inv_SM  = 1.f / (SM  + PRECS);
    const float inv_SMM = 1.f / (SMM + PRECS);
    const float oneK = 1.f - KI - KG;
    const float omCI = 1.f - CI, omCG = 1.f - CG;
    const float CWLM = C * WLM;
    const float inv1p = 1.f / (1.f + PRECS);
    // exact floor of ratio_s when S_eq hits the SM clamp: 1 - SM*inv_SM
    const float eps2  = fmaxf(PRECS, fmaf(-SM, inv_SM, 1.f));
    const float powPRECS = fpow(PRECS, invB);   // base_W floor thru ^invB

    const float* xg = x + (size_t)g * 3;

    if (threadIdx.x < 8) flg[threadIdx.x] = 0;
    __syncthreads();   // the only barrier

    if (wid == 0) {
        // ================= A: W-chain =================
        float WU = 0.001f, WL = 0.001f, WD = 0.001f;
        float pw1;
        {
            const float W0 = 0.003f;
            pw1 = fpow(fmaxf(fmaf(-W0, inv_WM, 1.f), PRECS), invB);
        }
        float weC0   = fmaxf(WL - CWLM, 0.f);
        float wrC    = weC0 * frcp(1.f + weC0);
        float wlinvC = WL * inv_WLM;

        for (int pblk = 0; pblk < NBLK; ++pblk) {
            waitge(&flg[0], pblk + 1);       // input pblk staged
            waitge(&flg[3], pblk - 3);       // stA[pblk&3] free: B done
            waitge(&flg[2], pblk - 3);       //                   C-FR done
            waitge(&flg[4], pblk - 3);       //                   D done
            float2 rin[K];
#pragma unroll
            for (int k = 0; k < K; ++k)
                rin[k] = stIn[pblk & 3][k][lane];
#pragma unroll
            for (int k = 0; k < K; ++k) {
                const float Pt = rin[k].x, PET_t = rin[k].y;
                const float PETmP = PET_t - Pt;
                const float capD  = fmaxf(wdm, WD);
                const float M0 = fminf(PETmP, WU);          // = P - EU (exact)
                const float D  = fmaxf(PETmP - WU, 0.f);
                const float ELwet = D * wlinvC;
                const float CD    = C * D;
                const float ELdry = fminf(CD, WL);
                const float EL    = med3(fmaf(wrC, ELwet - ELdry, ELdry), 0.f, WL);
                const float ED    = med3(fmaf(-C, EL, CD), 0.f, WD);
                const float SUME  = (M0 + EL) + ED;         // = E - P
                const float PE    = fmaxf(-SUME, 0.f);
                const float E     = Pt + SUME;
                const float W     = (WU + WL) + WD;
                // ONE pow on the carried cycle (pw1 carried)
                const float omr   = fmaxf(fmaf(-PE, inv_WMM, pw1), 0.f);
                const float powr  = fpow(omr, expB);
                const float R_per = fmaxf(fmaf(WM, powr, PE + (W - WM)), 0.f);
                // dry-path pow runs parallel to the powr branch
                const float bwd  = fmaxf(fmaf(-(W - SUME), inv_WM, 1.f), PRECS);
                const float pw1d = fpow(bwd, invB);
                pw1 = (SUME < 0.f) ? fmaxf(omr, powPRECS) : pw1d;
                // unified signed-residual cascade (exact both signs of dW)
                const float c0  = (WU - SUME) - R_per;
                const float WUn = med3(c0, 0.f, WUM);
                const float c1  = WL + (c0 - WUn);
                const float WLn = med3(c1, 0.f, WLM);
                const float c2  = WD + (c1 - WLn);
                const float WDn = med3(c2, 0.f, capD);
                WU = WUn; WL = WLn; WD = WDn;
                const float weN = fmaxf(WLn - CWLM, 0.f);
                wrC    = weN * frcp(1.f + weN);
                wlinvC = WLn * inv_WLM;
                stA[pblk & 3][k][lane] =
                    make_float4(PE, R_per, E, PE * inv_SMM);
            }
            setflag(&flg[1], pblk + 1);
        }
    } else if (wid == 1) {
        // ================= B: S-chain (the pacer) =================
        float Snc = 0.001f / oneK;   // pre-oneK S
        for (int pblk = 0; pblk < NBLK; ++pblk) {
            waitge(&flg[1], pblk + 1);       // stA[pblk] ready
            waitge(&flg[2], pblk + 1);       // stFR[pblk] ready
            waitge(&flg[4], pblk - 1);       // stB[pblk&1] free (D done)
            float4 ra[K], rf[K];
#pragma unroll
            for (int k = 0; k < K; ++k) ra[k] = stA[pblk & 3][k][lane];
#pragma unroll
            for (int k = 0; k < K; ++k) rf[k] = stFR[pblk & 1][k][lane];
#pragma unroll
            for (int k = 0; k < K; ++k) {
                const float PE = ra[k].x, R_per = ra[k].y, PEc = ra[k].w;
                const float FR = rf[k].x, r2 = rf[k].y;
                const float giFR = rf[k].z, RpiFR = rf[k].w;
                // off-chain helpers (short hops from Snc / constants)
                const float S_eq = fminf(Snc * giFR, SM);
                const float ReS  = RpiFR + S_eq;
                const float Kq   = (SM - PE) + RpiFR;
                // carried cycle: 4 trans + 8 VALU hops
                const float ratio_s = fmaxf(fmaf(-Snc, r2, 1.f), eps2);
                const float u   = fpow(ratio_s, invEX);
                const float om2 = fmaxf(u - PEc, 0.f);
                const float q   = fpow(om2, expEX);
                // med3 shift-identity: Sn = S_eq + med3(T+corr, 0, RpiFR)
                const float Sn  = med3(fmaf(-SM, q, Kq), S_eq, ReS);
                // RS output only (off the carry)
                const float RS = med3(fmaf(SM, q, (PE - SM) + S_eq) * FR,
                                      0.f, R_per);
                stB[pblk & 1][k][lane] = make_float2(RS, FR * Sn);
                Snc = Sn;
            }
            setflag(&flg[3], pblk + 1);
        }
    } else if (wid == 2) {
        // ================= C: loader + FR resolve =================
        float FRc = 0.001f, iFRc = frcp(0.001f + PRECS);
        float Pr[K], Er[K];
        // prime input blocks 0 and 1
#pragma unroll 1
        for (int j = 0; j < 2; ++j) {
#pragma unroll
            for (int k = 0; k < K; ++k) {
                const float* xq = xg + (size_t)(j * K + k) * xstride;
                Pr[k] = xq[0]; Er[k] = xq[2];
            }
#pragma unroll
            for (int k = 0; k < K; ++k)
                stIn[j][k][lane] = make_float2(Pr[k], Er[k] * KE);
            setflag(&flg[0], j + 1);
        }
        for (int j = 0; j < NBLK; ++j) {
            const bool ld = (j + 2 < NBLK);
            if (ld) {                        // issue loads early, ungated
#pragma unroll
                for (int k = 0; k < K; ++k) {
                    int t = (j + 2) * K + k;
                    t = (t < Nstep) ? t : Nstep - 1;
                    const float* xq = xg + (size_t)t * xstride;
                    Pr[k] = xq[0]; Er[k] = xq[2];
                }
            }
            waitge(&flg[1], j + 1);          // stA[j] ready (also stIn gate)
            waitge(&flg[3], j - 1);          // stFR[j&1] free (B done j-2)
#pragma unroll
            for (int k = 0; k < K; ++k) {
                const float4 ra = stA[j & 3][k][lane];
                const float gk = oneK * FRc;           // oneK*FR_{k-1}
                const float qq = frcp(ra.x + PRECS);
                const float aa = ra.y * qq;
                const float FRn  = fminf(aa, 1.f);
                const float iFRn = fmaxf(frcp(aa + PRECS), inv1p);
                const bool wet = ra.x > 0.f;
                FRc  = wet ? FRn  : FRc;
                iFRc = wet ? iFRn : iFRc;
                const float giFR = gk * iFRc;
                stFR[j & 1][k][lane] =
                    make_float4(FRc, giFR * inv_SM, giFR, ra.y * iFRc);
            }
            setflag(&flg[2], j + 1);
            if (ld) {
#pragma unroll
                for (int k = 0; k < K; ++k)
                    stIn[(j + 2) & 3][k][lane] = make_float2(Pr[k], Er[k] * KE);
                setflag(&flg[0], j + 3);
            }
        }
    } else {
        // ================= D: EMA + reduce + store =================
        float QI = 0.001f, QG = 0.001f;
        const float cKI = omCI * KI, cKG = omCG * KG;
        const float wa = (m == 0 || m == 1) ? 0.125f : 0.f;
        const float wb = (m == 0 || m == 2) ? 0.125f : 0.f;
        const float wc = (m == 0 || m == 3) ? 0.125f : 0.f;
        const float wd = (m >= 4) ? 0.125f : 0.f;
        const int   col = (m < 4) ? m : 4;
        float* outp = out + (size_t)g * 5 + col;
        const size_t ostr = (size_t)Ngrid * 5;

        for (int pblk = 0; pblk < NBLK; ++pblk) {
            waitge(&flg[3], pblk + 1);       // stB[pblk] ready (implies stA)
            float2 rb[K];
            float  re[K];
#pragma unroll
            for (int k = 0; k < K; ++k) rb[k] = stB[pblk & 1][k][lane];
#pragma unroll
            for (int k = 0; k < K; ++k) re[k] = stA[pblk & 3][k][lane].z;
            const int t0 = pblk * K;
#pragma unroll
            for (int k = 0; k < K; ++k) {
                QI = fmaf(CI, QI, cKI * rb[k].y);
                QG = fmaf(CG, QG, cKG * rb[k].y);
                const float u0 = rsum8(rb[k].x);
                const float u1 = rsum8(QI);
                const float u2 = rsum8(QG);
                const float u3 = rsum8(re[k]);
                const float v = fmaf(u0, wa, fmaf(u1, wb, fmaf(u2, wc, u3 * wd)));
                if (t0 + k < Nstep)
                    outp[(size_t)(t0 + k) * ostr] = v;
            }
            setflag(&flg[4], pblk + 1);
        }
    }
}

extern "C" void kernel_launch(void* const* d_in, const int* in_sizes, int n_in,
                              void* d_out, int out_size, void* d_ws, size_t ws_size,
                              hipStream_t stream) {
    const float* x   = (const float*)d_in[0];
    const float* prm = (const float*)d_in[1];
    float* out = (float*)d_out;
    xaj_kernel<<<250, 256, 0, stream>>>(x, prm, out);
}